// Round 6
// baseline (2937.033 us; speedup 1.0000x reference)
//
#include <hip/hip_runtime.h>

// SplineConv on MI355X (gfx950). fp32 in / fp32 out. R5 passed (absmax 3.9e-3).
// R6: fix k_main scatter — native LDS fp atomics (unsafeAtomicAdd -> ds_add_f32),
// chunked per-wave edge ownership (kills cross-wave same-address contention),
// group-of-8 load pipelining (overlaps rec/x latency).
//
// Pipeline: K0 wt bf16 transpose -> memset deg -> K1 deg -> K2 scan -> K3 records
//   -> K4 fused: LDS acc[16][1668] fp32, ds_add_f32 scatter, MFMA conv epilogue,
//      exact fp32 root term.

#define NN   50000
#define EE   1600000
#define NPB  16
#define KD   1664            // 26*64: 25 conv slices + 1 zero pad slice (MFMA k-multiple)
#define AST  1668            // padded LDS row stride (floats)
#define GRP  8               // edge pipeline depth per wave

typedef unsigned short ushort_t;
typedef __attribute__((ext_vector_type(8))) short short8;
typedef __attribute__((ext_vector_type(4))) float f32x4;

static __device__ __forceinline__ ushort_t f2bf(float f) {
  union { float f; unsigned u; } v; v.f = f;
  return (ushort_t)((v.u + 0x7fffu + ((v.u >> 16) & 1u)) >> 16);  // RNE
}

// ---------------- K0: wt[o*1664+k] = bf16(weight[k*64+o]) for k<1600, else 0
__global__ void k_wt(const float* __restrict__ w, ushort_t* __restrict__ wt) {
  int idx = blockIdx.x * 256 + threadIdx.x;          // over 64*1664
  if (idx >= 64 * KD) return;
  int o = idx / KD, k = idx - o * KD;
  wt[idx] = (k < 1600) ? f2bf(w[k * 64 + o]) : (ushort_t)0;
}

// ---------------- K1: degree count
__global__ void k_deg(const int* __restrict__ ei, int* __restrict__ deg) {
  int e = blockIdx.x * 256 + threadIdx.x;
  if (e < EE) atomicAdd(&deg[ei[e]], 1);
}

// ---------------- K2: single-block exclusive scan -> rowptr[N+1], cursor[N]
__global__ __launch_bounds__(1024) void k_scan(const int* __restrict__ deg,
                                               int* __restrict__ rowptr,
                                               int* __restrict__ cursor) {
  __shared__ int wsum[16];
  __shared__ int carry;
  const int t = threadIdx.x, lane = t & 63, wid = t >> 6;
  if (t == 0) carry = 0;
  __syncthreads();
  for (int base = 0; base < NN; base += 1024) {
    int i = base + t;
    int v = (i < NN) ? deg[i] : 0;
    int s = v;
    for (int off = 1; off < 64; off <<= 1) {
      int u = __shfl_up(s, off);
      if (lane >= off) s += u;
    }
    if (lane == 63) wsum[wid] = s;
    __syncthreads();
    int woff = 0;
    for (int j = 0; j < 16; ++j) { if (j < wid) woff += wsum[j]; }
    int c = carry;
    if (i < NN) { int ex = c + woff + s - v; rowptr[i] = ex; cursor[i] = ex; }
    __syncthreads();
    if (t == 1023) carry = c + woff + s;
    __syncthreads();
  }
  if (threadIdx.x == 0) rowptr[NN] = carry;
}

// ---------------- K3: 16B edge records {col, ln|base<<8, fr0, fr1}
__global__ void k_rec(const int* __restrict__ ei, const float* __restrict__ pseudo,
                      int* __restrict__ cursor, uint4* __restrict__ recs) {
  int e = blockIdx.x * 256 + threadIdx.x;
  if (e >= EE) return;
  int row = ei[e], col = ei[EE + e];
  float v0 = pseudo[2 * (long)e] * 4.0f;
  float v1 = pseudo[2 * (long)e + 1] * 4.0f;
  int lo0 = min((int)v0, 3), lo1 = min((int)v1, 3);   // clamp == reference %K wrap (basis 0 there)
  float fr0 = v0 - (float)lo0, fr1 = v1 - (float)lo1;
  int base = lo0 * 5 + lo1;
  int ln = row & (NPB - 1);
  int slot = atomicAdd(&cursor[row], 1);
  uint4 r;
  r.x = (unsigned)col;
  r.y = (unsigned)(ln | (base << 8));
  r.z = __float_as_uint(fr0);
  r.w = __float_as_uint(fr1);
  recs[slot] = r;
}

// ---------------- K4: main fused kernel. 1 block = 16 nodes, 1024 threads (16 waves)
__global__ __launch_bounds__(1024) void k_main(
    const uint4* __restrict__ recs, const int* __restrict__ rowptr,
    const float* __restrict__ x, const ushort_t* __restrict__ wt,
    const float* __restrict__ root, const float* __restrict__ bias,
    float* __restrict__ out) {
  __shared__ float acc[NPB * AST];     // ~104 KB; slice [1600,1664) stays zero (MFMA pad)
  __shared__ float outb[NPB * 64];     // 4 KB
  __shared__ float sinv[NPB];
  const int tid = threadIdx.x;
  const int nb = blockIdx.x * NPB;
  const int lane = tid & 63;
  const int ln0 = tid >> 6;

  {  // vectorized zero: 6672 float4s
    float4* a4 = (float4*)acc;
    const float4 z = make_float4(0.f, 0.f, 0.f, 0.f);
    for (int j = tid; j < (NPB * AST) / 4; j += 1024) a4[j] = z;
    ((float4*)outb)[tid & 255] = z;    // 256 float4s cover outb
  }
  if (lane == 0) {
    int node = nb + ln0;
    int dc = max(rowptr[node + 1] - rowptr[node], 1);
    sinv[ln0] = 1.0f / (float)dc;
  }
  const int wid = __builtin_amdgcn_readfirstlane(tid >> 6);
  const int eBeg = rowptr[nb], eEnd = rowptr[nb + NPB];
  __syncthreads();

  // edge scatter: chunked per-wave ownership (one wave ~= one node's edges),
  // group-of-8 pipelined loads, fire-and-forget native ds_add_f32.
  {
    const int total = eEnd - eBeg;
    const int C = (total + NPB - 1) >> 4;           // chunk per wave
    const int cb = eBeg + wid * C;
    const int ce = min(cb + C, eEnd);
    for (int g = cb; g < ce; g += GRP) {
      uint4 rg[GRP];
#pragma unroll
      for (int j = 0; j < GRP; ++j) {
        int e = g + j; e = (e < EE) ? e : (EE - 1);
        rg[j] = recs[e];                             // uniform (scalar) loads, contiguous
      }
      float xs[GRP], w0[GRP], w1[GRP], w2[GRP], w3[GRP];
      int ofs[GRP];
#pragma unroll
      for (int j = 0; j < GRP; ++j) {
        int col = (int)rg[j].x;
        int l2  = (int)(rg[j].y & 255u);
        int bs  = (int)(rg[j].y >> 8);
        float fr0 = __uint_as_float(rg[j].z);
        float fr1 = __uint_as_float(rg[j].w);
        float m  = (g + j < ce) ? 1.0f : 0.0f;       // tail mask (addr stays valid)
        float g0 = 1.0f - fr0, g1 = 1.0f - fr1;
        w0[j] = g0 * g1 * m;  w1[j] = g0 * fr1 * m;
        w2[j] = fr0 * g1 * m; w3[j] = fr0 * fr1 * m;
        ofs[j] = l2 * AST + (bs << 6);
        xs[j] = x[(size_t)col * 64 + lane];          // 8 coalesced row loads in flight
      }
#pragma unroll
      for (int j = 0; j < GRP; ++j) {
        float* ap = &acc[ofs[j] + lane];
        float v = xs[j];
        unsafeAtomicAdd(ap,       w0[j] * v);        // ds_add_f32, no return, no retry
        unsafeAtomicAdd(ap + 64,  w1[j] * v);
        unsafeAtomicAdd(ap + 320, w2[j] * v);
        unsafeAtomicAdd(ap + 384, w3[j] * v);
      }
    }
  }
  __syncthreads();

  {  // conv epilogue GEMM: D[16 nodes][64 out] = acc[16][1664] @ wt^T
     // 16 waves = 4 n-tiles x 4 k-quarters (416 each = 13 MFMA)
    const int ntile = wid & 3, kh = wid >> 2;
    const int m = lane & 15, quad = lane >> 4;
    const int nn2 = ntile * 16 + m;
    f32x4 d = {0.0f, 0.0f, 0.0f, 0.0f};
    const float*    ab = &acc[m * AST + kh * 416 + quad * 8];
    const ushort_t* wb = &wt[(size_t)nn2 * KD + kh * 416 + quad * 8];
    for (int kk = 0; kk < 13; ++kk) {
      float4 a0 = *(const float4*)(ab + kk * 32);
      float4 a1 = *(const float4*)(ab + kk * 32 + 4);
      short8 af;
      af[0] = (short)f2bf(a0.x); af[1] = (short)f2bf(a0.y);
      af[2] = (short)f2bf(a0.z); af[3] = (short)f2bf(a0.w);
      af[4] = (short)f2bf(a1.x); af[5] = (short)f2bf(a1.y);
      af[6] = (short)f2bf(a1.z); af[7] = (short)f2bf(a1.w);
      short8 bf = *(const short8*)(wb + kk * 32);
      d = __builtin_amdgcn_mfma_f32_16x16x32_bf16(af, bf, d, 0, 0, 0);
    }
    // D layout: col(out-feature-in-tile)=lane&15, row(node)=quad*4+reg  [m89/m91]
    float* ob = &outb[ntile * 16 + m];
    int r0 = quad * 4;
    unsafeAtomicAdd(ob + (r0 + 0) * 64, d[0]);
    unsafeAtomicAdd(ob + (r0 + 1) * 64, d[1]);
    unsafeAtomicAdd(ob + (r0 + 2) * 64, d[2]);
    unsafeAtomicAdd(ob + (r0 + 3) * 64, d[3]);
  }
  __syncthreads();

  {  // out[node][o] = conv/clip(deg,1) + x[node]@root[:,o] + bias[o]   (fp32 exact root)
    const int node = nb + ln0;
    const float* xrow = &x[(size_t)node * 64];
    float r0 = bias[lane], r1 = 0.f, r2 = 0.f, r3 = 0.f;
    for (int i = 0; i < 64; i += 4) {
      r0 += xrow[i]     * root[(size_t)i * 64 + lane];
      r1 += xrow[i + 1] * root[(size_t)(i + 1) * 64 + lane];
      r2 += xrow[i + 2] * root[(size_t)(i + 2) * 64 + lane];
      r3 += xrow[i + 3] * root[(size_t)(i + 3) * 64 + lane];
    }
    out[(size_t)node * 64 + lane] = outb[tid] * sinv[ln0] + ((r0 + r1) + (r2 + r3));
  }
}

// ---------------- sentinel: unambiguous "workspace too small" signature
__global__ void k_sentinel(float* __restrict__ out) {
  int i = blockIdx.x * 256 + threadIdx.x;
  if (i < NN * 64) out[i] = 1000.0f;
}

extern "C" void kernel_launch(void* const* d_in, const int* in_sizes, int n_in,
                              void* d_out, int out_size, void* d_ws, size_t ws_size,
                              hipStream_t stream) {
  const float* x      = (const float*)d_in[0];
  const int*   ei     = (const int*)d_in[1];
  const float* pseudo = (const float*)d_in[2];
  const float* w      = (const float*)d_in[3];
  const float* root   = (const float*)d_in[4];
  const float* bias   = (const float*)d_in[5];
  float* out = (float*)d_out;

  char* ws = (char*)d_ws;
  size_t off = 0;
  auto alloc = [&](size_t bytes) { size_t r = off; off += (bytes + 511) & ~(size_t)511; return r; };
  ushort_t* wt     = (ushort_t*)(ws + alloc((size_t)64 * KD * 2));   // 212,992 B
  int*      rowptr = (int*)(ws + alloc((size_t)(NN + 1) * 4));
  int*      cursor = (int*)(ws + alloc((size_t)NN * 4));
  int*      deg    = (int*)(ws + alloc((size_t)NN * 4));
  uint4*    recs   = (uint4*)(ws + alloc((size_t)EE * 16));          // 25.6 MB
  (void)in_sizes; (void)n_in; (void)out_size;

  if (ws_size < off) {  // ~26.4 MB needed
    k_sentinel<<<(NN * 64 + 255) / 256, 256, 0, stream>>>(out);
    return;
  }

  k_wt<<<(64 * KD + 255) / 256, 256, 0, stream>>>(w, wt);
  hipMemsetAsync(deg, 0, (size_t)NN * 4, stream);
  k_deg<<<(EE + 255) / 256, 256, 0, stream>>>(ei, deg);
  k_scan<<<1, 1024, 0, stream>>>(deg, rowptr, cursor);
  k_rec<<<(EE + 255) / 256, 256, 0, stream>>>(ei, pseudo, cursor, recs);
  k_main<<<NN / NPB, 1024, 0, stream>>>(recs, rowptr, x, wt, root, bias, out);
}